// Round 13
// baseline (334.015 us; speedup 1.0000x reference)
//
#include <hip/hip_runtime.h>
#include <hip/hip_bf16.h>

// ---------------------------------------------------------------------------
// ROUND 32: double k_attn wave count via intra-block t-split. R31 post-mortem:
// compiler register-allocated the 16-deep batch down to ~6-8 in flight
// (VGPR 44) -- in-flight-bytes lever defeated; mask stream accepted at
// 3.3 TB/s. k_attn (~60us, #2) is GRID-starved: 4000 waves = 15.6/CU at
// VGPR 56 (9/SIMD possible). Change: 256-thr blocks, 4 waves =
// (head hd, t-half hf); wave runs slice s=jy*2+hf (~31 iters); halves
// combined via 10KB LDS + 1 barrier (R18 trick on R25 slim structure);
// hf=0 stores. partAcc slot (jy*2+hd) and k_final BYTE-IDENTICAL; ws
// unchanged. Waves 4000->8000 (~31/CU).
// Predict: k_attn occ 33->55-70%, VALU ->65-75%, dur ~60->45-50;
// total 329.7 -> ~315-320. k_front unchanged.
// Carried: pack||wh fusion + 16-deep NT batch (R31), one-head waves (R25),
// packed-E2 exp-free loop (R29), k_mid fusion (R27).
// ---------------------------------------------------------------------------

#define CN1 3000
#define CN2 2500
#define CN3 2500
#define NTOT 8000
#define INF_ 128
#define OUTF 64
#define LOG2E 1.44269504088896340736f
#define ALPHA 0.2f

typedef __attribute__((ext_vector_type(4))) float f32x4;
typedef __attribute__((ext_vector_type(8))) short short8;
typedef __attribute__((ext_vector_type(4))) int i32x4;
union B16x8 { int4 i4; short8 s8; unsigned int u[4]; };

#if defined(__has_builtin)
#if __has_builtin(__builtin_amdgcn_exp2f)
#define EXP2F(x) __builtin_amdgcn_exp2f(x)
#endif
#endif
#ifndef EXP2F
#define EXP2F(x) exp2f(x)
#endif

__device__ inline float wave_sum(float v) {
  for (int d = 32; d; d >>= 1) v += __shfl_xor(v, d, 64);
  return v;
}

// packed RNE f32x2 -> bf16x2 (v_cvt_pk_bf16_f32 on gfx950 via hip header)
__device__ inline unsigned int pk2(float a, float b) {
  union { __hip_bfloat162 h; unsigned int u; } cv;
  cv.h = __float22bfloat162_rn(make_float2(a, b));
  return cv.u;
}

__device__ inline unsigned int pack2_bf16(float a, float b) {
  unsigned ua = __float_as_uint(a);
  ua = (ua + 0x7FFFu + ((ua >> 16) & 1u)) >> 16;
  unsigned ub = __float_as_uint(b);
  ub = (ub + 0x7FFFu + ((ub >> 16) & 1u)) & 0xFFFF0000u;
  return ub | ua;
}

// ---------------- k_front: even blocks = mask-pack, odd blocks = Wh ---------
__global__ __launch_bounds__(256)
void k_front(const int* __restrict__ A1,  const int* __restrict__ A12, const int* __restrict__ A13,
             const int* __restrict__ A21, const int* __restrict__ A2,  const int* __restrict__ A23,
             const int* __restrict__ A31, const int* __restrict__ A32, const int* __restrict__ A3,
             unsigned int* __restrict__ packed,
             const float* __restrict__ hv, const float* __restrict__ Wsv,
             const float* __restrict__ ap,
             float* __restrict__ Whf,    // [2][8000][64]
             float* __restrict__ Wh1s,   // [2][8000] = (Wh·a1)*log2e
             float* __restrict__ Wh2s,   // [2][8000] = (Wh·a2)*log2e (for m2)
             unsigned int* __restrict__ E2pk) { // [2][8000] packed bf16 pair
  if ((blockIdx.x & 1) == 0) {
    // ---- pack role: row-group pk = blockIdx.x/2, 4 waves = 4 rows ----
    const int i = (blockIdx.x >> 1) * 4 + (threadIdx.x >> 6);
    const int lane = threadIdx.x & 63;
    const int *r0, *r1, *r2;
    if (i < CN1)            { r0 = A1  + i * CN1;          r1 = A12 + i * CN2;          r2 = A13 + i * CN3; }
    else if (i < CN1 + CN2) { int r = i - CN1;       r0 = A21 + r * CN1; r1 = A2  + r * CN2; r2 = A23 + r * CN3; }
    else                    { int r = i - CN1 - CN2; r0 = A31 + r * CN1; r1 = A32 + r * CN2; r2 = A3  + r * CN3; }
    const i32x4* p0 = (const i32x4*)r0;   // 750 int4 (cols    0..2999)
    const i32x4* p1 = (const i32x4*)r1;   // 625 int4 (cols 3000..5499)
    const i32x4* p2 = (const i32x4*)r2;   // 625 int4 (cols 5500..7999)
    unsigned int* pkrow = packed + (i >> 4) * 4000 + (i & 15);
    const int sh = 4 * (lane & 7);
    const int w  = lane >> 3;
#pragma unroll
    for (int ob = 0; ob < 2; ++ob) {
      i32x4 v[16];
#pragma unroll
      for (int u = 0; u < 16; ++u) {
        int q = (ob * 16 + u) * 64 + lane;
        q = q < 2000 ? q : 1999;                   // clamp (it=31 partial)
        const i32x4* src = (q < 750) ? (p0 + q) : (q < 1375) ? (p1 + q - 750) : (p2 + q - 1375);
        v[u] = __builtin_nontemporal_load(src);
      }
#pragma unroll
      for (int u = 0; u < 16; ++u) {
        const int it = ob * 16 + u;
        const bool act = (it * 64 + lane) < 2000;
        unsigned int n = (v[u].x > 0 ? 1u : 0u) | (v[u].y > 0 ? 2u : 0u)
                       | (v[u].z > 0 ? 4u : 0u) | (v[u].w > 0 ? 8u : 0u);
        n = act ? (n << sh) : 0u;
        n |= __shfl_xor(n, 1, 64);
        n |= __shfl_xor(n, 2, 64);
        n |= __shfl_xor(n, 4, 64);                 // all 8 lanes of group hold word
        const int wglob = it * 8 + w;
        if ((lane & 7) == 0 && wglob < 250)
          pkrow[wglob * 16] = n;
      }
    }
  } else {
    // ---- wh role: node-group nb = blockIdx.x/2, 4 waves = 4 nodes ----
    const int t = threadIdx.x;
    const int o = t & 63;
    const int n = (blockIdx.x >> 1) * 4 + (t >> 6);
    const float* hrow = hv + n * INF_;
    const float* Ws0 = Wsv + o;
    const float* Ws1 = Wsv + INF_ * OUTF + o;
    float a0a = 0.f, a0b = 0.f, a1a = 0.f, a1b = 0.f;
#pragma unroll 8
    for (int f = 0; f < INF_; f += 2) {
      float h0 = hrow[f], h1 = hrow[f + 1];
      a0a += h0 * Ws0[f * OUTF];
      a0b += h1 * Ws0[(f + 1) * OUTF];
      a1a += h0 * Ws1[f * OUTF];
      a1b += h1 * Ws1[(f + 1) * OUTF];
    }
    float acc0 = a0a + a0b, acc1 = a1a + a1b;
    Whf[(0 * NTOT + n) * OUTF + o] = acc0;
    Whf[(1 * NTOT + n) * OUTF + o] = acc1;
    float s10 = wave_sum(acc0 * ap[o]);
    float s20 = wave_sum(acc0 * ap[OUTF + o]);
    float s11 = wave_sum(acc1 * ap[2 * OUTF + o]);
    float s21 = wave_sum(acc1 * ap[3 * OUTF + o]);
    if (o == 0) {
      const float w20 = s20 * LOG2E, w21 = s21 * LOG2E;
      Wh1s[n] = s10 * LOG2E;        Wh2s[n] = w20;
      Wh1s[NTOT + n] = s11 * LOG2E; Wh2s[NTOT + n] = w21;
      E2pk[n]        = pk2(EXP2F(w20), EXP2F(ALPHA * w20)); // lo=E2p hi=E2n
      E2pk[NTOT + n] = pk2(EXP2F(w21), EXP2F(ALPHA * w21));
    }
  }
}

// ---------------- k_mid: blocks 0-1 = m2 (global max), 2..501 = bpack -------
__global__ __launch_bounds__(256)
void k_mid(const float* __restrict__ Whf, const float* __restrict__ Wh2s,
           float* __restrict__ M2s, int4* __restrict__ WhB) {
  if (blockIdx.x < 2) {
    const int hd = blockIdx.x;
    float mx = -1e30f;
    for (int i = threadIdx.x; i < NTOT; i += 256)
      mx = fmaxf(mx, Wh2s[hd * NTOT + i]);
    for (int d = 32; d; d >>= 1) mx = fmaxf(mx, __shfl_xor(mx, d, 64));
    __shared__ float red[4];
    if ((threadIdx.x & 63) == 0) red[threadIdx.x >> 6] = mx;
    __syncthreads();
    if (threadIdx.x == 0)
      M2s[hd] = fmaxf(fmaxf(red[0], red[1]), fmaxf(red[2], red[3]));
  } else {
    const int gid = (blockIdx.x - 2) * 256 + threadIdx.x;  // 128000 total
    const int lane = gid & 63;
    const int c = (gid >> 6) & 3;
    const int t = (gid >> 8) % 250;
    const int hd = gid / 64000;
    const int jb = t * 32 + (lane >> 4) * 8;
    const int col = c * 16 + (lane & 15);
    const float* src = Whf + (hd * NTOT + jb) * OUTF + col;
    B16x8 out;
#pragma unroll
    for (int e2 = 0; e2 < 4; ++e2)
      out.u[e2] = pack2_bf16(src[(2 * e2) * OUTF], src[(2 * e2 + 1) * OUTF]);
    WhB[gid] = out.i4;
  }
}

// ---------------- k_attn_mfma: grid=(500, njy), block=256 -------------------
// 4 waves = (head hd, t-half hf); wave runs slice s=jy*2+hf; LDS combine
// halves per head; hf=0 stores slot (jy*2+hd) -- k_final layout unchanged.
__global__ __launch_bounds__(256)
void k_attn_mfma(const unsigned int* __restrict__ packed,
                 const float* __restrict__ Wh1s,
                 const float* __restrict__ M2s, const int4* __restrict__ WhB,
                 const unsigned int* __restrict__ E2pk,  // [2][8000]
                 float* __restrict__ partAcc,   // [njy][2][8000][64]
                 float* __restrict__ partS)     // [njy][2][8000]
{
  const int hd = threadIdx.x >> 7;               // head index (0/1)
  const int hf = (threadIdx.x >> 6) & 1;         // t-half (0/1)
  const int lane = threadIdx.x & 63;
  const int m = lane & 15;
  const int g = lane >> 4;
  const int kb = g * 8;
  const int rowblk = blockIdx.x;                 // 0..499
  const int i = rowblk * 16 + m;
  const int jy = blockIdx.y, njy = gridDim.y;
  const int s = jy * 2 + hf, ns = njy * 2;       // t-slice index
  const int t0 = (250 * s) / ns, t1 = (250 * (s + 1)) / ns;

  const unsigned int* pkb = packed + rowblk * 4000 + m;

  const float w1s = Wh1s[hd * NTOT + i];
  const float y = w1s + M2s[hd];
  const float ci = fmaxf(y, ALPHA * y);
  const float E1p = EXP2F(w1s - ci);
  const float E1n = EXP2F(fmaf(ALPHA, w1s, -ci));
  const unsigned int* e2 = E2pk + hd * NTOT;
  const int4* WhBh = WhB + hd * 64000;           // 250*256 frags per head

  f32x4 a_0 = {0.f,0.f,0.f,0.f}, a_1 = a_0, a_2 = a_0, a_3 = a_0;
  f32x4 sv = a_0;                                // ones-MFMA row sums

  B16x8 ones;                                     // bf16 1.0 x8
#pragma unroll
  for (int e2i = 0; e2i < 4; ++e2i) ones.u[e2i] = 0x3F803F80u;

  struct Frags { int4 f[4]; uint4 ua, ub; };
  auto load_frags = [&](int t, Frags& F) {
    const int4* bp = WhBh + t * 256 + lane;
#pragma unroll
    for (int c = 0; c < 4; ++c) F.f[c] = bp[c * 64];
    const unsigned int* w0 = e2 + t * 32 + kb;
    F.ua = *(const uint4*)w0; F.ub = *(const uint4*)(w0 + 4);
  };

  auto compute = [&](unsigned int mw, const Frags& F) {
    const unsigned bits = (mw >> kb) & 0xffu;
    const unsigned uv[8] = {F.ua.x, F.ua.y, F.ua.z, F.ua.w, F.ub.x, F.ub.y, F.ub.z, F.ub.w};
    float q[8];
#pragma unroll
    for (int e = 0; e < 8; ++e) {
      bool on = ((bits >> e) & 1u) != 0u;
      float p = __uint_as_float(uv[e] << 16);            // E2p (bf16->f32)
      float nn = __uint_as_float(uv[e] & 0xFFFF0000u);   // E2n
      float v = fmaxf(E1p * p, E1n * nn);
      q[e] = on ? v : 0.f;
    }
    B16x8 af;
#pragma unroll
    for (int e2i = 0; e2i < 4; ++e2i)
      af.u[e2i] = pk2(q[2 * e2i], q[2 * e2i + 1]);
    B16x8 b;
    b.i4 = F.f[0]; a_0 = __builtin_amdgcn_mfma_f32_16x16x32_bf16(af.s8, b.s8, a_0, 0, 0, 0);
    b.i4 = F.f[1]; a_1 = __builtin_amdgcn_mfma_f32_16x16x32_bf16(af.s8, b.s8, a_1, 0, 0, 0);
    b.i4 = F.f[2]; a_2 = __builtin_amdgcn_mfma_f32_16x16x32_bf16(af.s8, b.s8, a_2, 0, 0, 0);
    b.i4 = F.f[3]; a_3 = __builtin_amdgcn_mfma_f32_16x16x32_bf16(af.s8, b.s8, a_3, 0, 0, 0);
    sv = __builtin_amdgcn_mfma_f32_16x16x32_bf16(af.s8, ones.s8, sv, 0, 0, 0);
  };

  // pipeline: mask word 2 ahead; frags 1 ahead via named FA/FB (no copies)
  unsigned int mw0 = pkb[t0 * 16];
  unsigned int mw1 = pkb[min(t0 + 1, t1 - 1) * 16];
  Frags FA, FB;
  load_frags(t0, FA);
  int t = t0;
  for (; t + 1 < t1; t += 2) {
    load_frags(t + 1, FB);
    unsigned int mwa = pkb[min(t + 2, t1 - 1) * 16];
    compute(mw0, FA);
    mw0 = mw1; mw1 = mwa;
    load_frags(min(t + 2, t1 - 1), FA);
    unsigned int mwb = pkb[min(t + 3, t1 - 1) * 16];
    compute(mw0, FB);
    mw0 = mw1; mw1 = mwb;
  }
  if (t < t1) compute(mw0, FA);                  // odd-length tail (FA = t1-1)

  // combine t-halves per head via LDS (hf=1 -> hf=0), then hf=0 stores
  __shared__ f32x4 lds[2][5][64];
  if (hf == 1) {
    lds[hd][0][lane] = a_0; lds[hd][1][lane] = a_1;
    lds[hd][2][lane] = a_2; lds[hd][3][lane] = a_3;
    lds[hd][4][lane] = sv;
  }
  __syncthreads();
  if (hf == 0) {
    a_0 += lds[hd][0][lane]; a_1 += lds[hd][1][lane];
    a_2 += lds[hd][2][lane]; a_3 += lds[hd][3][lane];
    sv  += lds[hd][4][lane];

    const int base = (jy * 2 + hd) * NTOT + rowblk * 16;
    if (m == 0) {
#pragma unroll
      for (int q = 0; q < 4; ++q)
        partS[base + g * 4 + q] = sv[q];
    }
    // C layout: col = lane&15 (feature), row = g*4 + q (node)
    float* o = partAcc + base * OUTF;
#pragma unroll
    for (int q = 0; q < 4; ++q) {
      const int row = g * 4 + q;
      o[row * OUTF +      m] = a_0[q];
      o[row * OUTF + 16 + m] = a_1[q];
      o[row * OUTF + 32 + m] = a_2[q];
      o[row * OUTF + 48 + m] = a_3[q];
    }
  }
}

// ---------------- k_final: combine njy + /s + ELU + log_softmax + store -----
__global__ void k_final(const float* __restrict__ partAcc, const float* __restrict__ partS,
                        int njy, float* __restrict__ out) {
  const int wave = threadIdx.x >> 6, lane = threadIdx.x & 63;
  const int n = blockIdx.x * 4 + wave;
  float x[2];
#pragma unroll
  for (int hd = 0; hd < 2; ++hd) {
    float a = 0.f, s = 0.f;
    for (int jy = 0; jy < njy; ++jy) {
      a += partAcc[((jy * 2 + hd) * NTOT + n) * OUTF + lane];
      s += partS[(jy * 2 + hd) * NTOT + n];
    }
    float mid = a / s;
    x[hd] = mid > 0.f ? mid : (__expf(mid) - 1.f);   // ELU(alpha=1)
  }
  float mx = fmaxf(x[0], x[1]);
  for (int d = 32; d; d >>= 1) mx = fmaxf(mx, __shfl_xor(mx, d, 64));
  float se = __expf(x[0] - mx) + __expf(x[1] - mx);
  for (int d = 32; d; d >>= 1) se += __shfl_xor(se, d, 64);
  const float lse = mx + __logf(se);
  const int orow = (n >= CN1 + CN2) ? (n - CN1 - CN2) : (n + CN3);
  out[orow * 128 + lane]      = x[0] - lse;
  out[orow * 128 + 64 + lane] = x[1] - lse;
}

__global__ void k_sentinel(float* __restrict__ out, float v) {
  out[blockIdx.x * 256 + threadIdx.x] = v;
}

// ---------------------------------------------------------------------------
extern "C" void kernel_launch(void* const* d_in, const int* in_sizes, int n_in,
                              void* d_out, int out_size, void* d_ws, size_t ws_size,
                              hipStream_t stream) {
  float* outf = (float*)d_out;

  static const int EXP[12] = {1024000, 9000000, 6250000, 6250000, 7500000, 7500000,
                              6250000, 7500000, 7500000, 6250000, 16384, 256};
  bool exact = (n_in == 12);
  if (exact) for (int i = 0; i < 12; ++i) if (in_sizes[i] != EXP[i]) { exact = false; break; }

  // ws layout: Wh1s 64000 | Wh2s 64000 | M2s 256 | E2pk 64000 | WhB 2,048,000 |
  //            packed 8,000,000 | partS njy*64,000 |
  //            Whf 4,096,000 / partAcc njy*4,096,000 (overlay)
  const size_t FIXED = 64000 + 64000 + 256 + 64000 + 2048000 + 8000000; // 10,240,256
  int njy = 0;
  for (int cand = 8; cand >= 1; cand >>= 1) {
    size_t need = FIXED + (size_t)cand * 64000 + (size_t)cand * 4096000;
    if (ws_size >= need) { njy = cand; break; }
  }
  if (!exact || njy == 0) {
    k_sentinel<<<dim3(4000), dim3(256), 0, stream>>>(outf, -148.0f);
    return;
  }

  const float* h  = (const float*)d_in[0];
  const int* A1  = (const int*)d_in[1];
  const int* A2  = (const int*)d_in[2];
  const int* A3  = (const int*)d_in[3];
  const int* A12 = (const int*)d_in[4];
  const int* A13 = (const int*)d_in[5];
  const int* A23 = (const int*)d_in[6];
  const int* A21 = (const int*)d_in[7];
  const int* A31 = (const int*)d_in[8];
  const int* A32 = (const int*)d_in[9];
  const float* Ws = (const float*)d_in[10];
  const float* ap = (const float*)d_in[11];

  char* w = (char*)d_ws;
  float*        Wh1s    = (float*)(w);
  float*        Wh2s    = (float*)(w + 64000);
  float*        M2s     = (float*)(w + 128000);
  unsigned int* E2pk    = (unsigned int*)(w + 128256);
  int4*         WhB     = (int4*) (w + 192256);
  unsigned int* packed  = (unsigned int*)(w + 2240256);
  float*        partS   = (float*)(w + 10240256);
  float*        Whf     = (float*)(w + 10240256 + (size_t)njy * 64000);
  float*        partAcc = Whf;                    // overlay (Whf dead after k_mid)

  k_front    <<<dim3(4000),     dim3(256), 0, stream>>>(A1, A12, A13, A21, A2, A23, A31, A32, A3,
                                                        packed, h, Ws, ap, Whf, Wh1s, Wh2s, E2pk);
  k_mid      <<<dim3(502),      dim3(256), 0, stream>>>(Whf, Wh2s, M2s, WhB);
  k_attn_mfma<<<dim3(500, njy), dim3(256), 0, stream>>>(packed, Wh1s, M2s, WhB, E2pk,
                                                        partAcc, partS);
  k_final    <<<dim3(2000),     dim3(256), 0, stream>>>(partAcc, partS, njy, outf);
}

// Round 14
// 329.518 us; speedup vs baseline: 1.0136x; 1.0136x over previous
//
#include <hip/hip_runtime.h>
#include <hip/hip_bf16.h>

// ---------------------------------------------------------------------------
// ROUND 33: revert R32 t-split (329.7->334; third failed occupancy fix).
// Re-derivation: k_attn reads 4KB WhB + 2KB E2 per t-iter x 4000 waves x 62
// iters ~= 1.5GB L2 traffic in ~60us ~= 25 TB/s ~= the 34.5 TB/s L2 ceiling
// => k_attn is L2-BANDWIDTH-bound (explains why occupancy and VALU cuts all
// failed, and why only footprint-slimming R25 helped). Fix = arithmetic
// intensity: TWO rowblks per wave (32 rows) share each WhB/E2 tile -> L2
// traffic halves (~0.8GB). 10 MFMAs/iter, 2 mask streams, VGPR ~100, grid
// (250,njy). partAcc/partS layout + k_final byte-identical.
// Predict: k_attn ~60 -> ~38-45us, VGPR ~96-112, occ ~15% (fine if BW-
// bound); total 329.7 -> ~312-318. If k_attn flat -> not BW-bound, plateau.
// Carried: pack||wh fusion + 16-deep NT batch (R31), one-head waves (R25),
// packed-E2 exp-free loop (R29), k_mid fusion (R27).
// ---------------------------------------------------------------------------

#define CN1 3000
#define CN2 2500
#define CN3 2500
#define NTOT 8000
#define INF_ 128
#define OUTF 64
#define LOG2E 1.44269504088896340736f
#define ALPHA 0.2f

typedef __attribute__((ext_vector_type(4))) float f32x4;
typedef __attribute__((ext_vector_type(8))) short short8;
typedef __attribute__((ext_vector_type(4))) int i32x4;
union B16x8 { int4 i4; short8 s8; unsigned int u[4]; };

#if defined(__has_builtin)
#if __has_builtin(__builtin_amdgcn_exp2f)
#define EXP2F(x) __builtin_amdgcn_exp2f(x)
#endif
#endif
#ifndef EXP2F
#define EXP2F(x) exp2f(x)
#endif

__device__ inline float wave_sum(float v) {
  for (int d = 32; d; d >>= 1) v += __shfl_xor(v, d, 64);
  return v;
}

// packed RNE f32x2 -> bf16x2 (v_cvt_pk_bf16_f32 on gfx950 via hip header)
__device__ inline unsigned int pk2(float a, float b) {
  union { __hip_bfloat162 h; unsigned int u; } cv;
  cv.h = __float22bfloat162_rn(make_float2(a, b));
  return cv.u;
}

__device__ inline unsigned int pack2_bf16(float a, float b) {
  unsigned ua = __float_as_uint(a);
  ua = (ua + 0x7FFFu + ((ua >> 16) & 1u)) >> 16;
  unsigned ub = __float_as_uint(b);
  ub = (ub + 0x7FFFu + ((ub >> 16) & 1u)) & 0xFFFF0000u;
  return ub | ua;
}

// ---------------- k_front: even blocks = mask-pack, odd blocks = Wh ---------
__global__ __launch_bounds__(256)
void k_front(const int* __restrict__ A1,  const int* __restrict__ A12, const int* __restrict__ A13,
             const int* __restrict__ A21, const int* __restrict__ A2,  const int* __restrict__ A23,
             const int* __restrict__ A31, const int* __restrict__ A32, const int* __restrict__ A3,
             unsigned int* __restrict__ packed,
             const float* __restrict__ hv, const float* __restrict__ Wsv,
             const float* __restrict__ ap,
             float* __restrict__ Whf,    // [2][8000][64]
             float* __restrict__ Wh1s,   // [2][8000] = (Wh·a1)*log2e
             float* __restrict__ Wh2s,   // [2][8000] = (Wh·a2)*log2e (for m2)
             unsigned int* __restrict__ E2pk) { // [2][8000] packed bf16 pair
  if ((blockIdx.x & 1) == 0) {
    // ---- pack role: row-group pk = blockIdx.x/2, 4 waves = 4 rows ----
    const int i = (blockIdx.x >> 1) * 4 + (threadIdx.x >> 6);
    const int lane = threadIdx.x & 63;
    const int *r0, *r1, *r2;
    if (i < CN1)            { r0 = A1  + i * CN1;          r1 = A12 + i * CN2;          r2 = A13 + i * CN3; }
    else if (i < CN1 + CN2) { int r = i - CN1;       r0 = A21 + r * CN1; r1 = A2  + r * CN2; r2 = A23 + r * CN3; }
    else                    { int r = i - CN1 - CN2; r0 = A31 + r * CN1; r1 = A32 + r * CN2; r2 = A3  + r * CN3; }
    const i32x4* p0 = (const i32x4*)r0;   // 750 int4 (cols    0..2999)
    const i32x4* p1 = (const i32x4*)r1;   // 625 int4 (cols 3000..5499)
    const i32x4* p2 = (const i32x4*)r2;   // 625 int4 (cols 5500..7999)
    unsigned int* pkrow = packed + (i >> 4) * 4000 + (i & 15);
    const int sh = 4 * (lane & 7);
    const int w  = lane >> 3;
#pragma unroll
    for (int ob = 0; ob < 2; ++ob) {
      i32x4 v[16];
#pragma unroll
      for (int u = 0; u < 16; ++u) {
        int q = (ob * 16 + u) * 64 + lane;
        q = q < 2000 ? q : 1999;                   // clamp (it=31 partial)
        const i32x4* src = (q < 750) ? (p0 + q) : (q < 1375) ? (p1 + q - 750) : (p2 + q - 1375);
        v[u] = __builtin_nontemporal_load(src);
      }
#pragma unroll
      for (int u = 0; u < 16; ++u) {
        const int it = ob * 16 + u;
        const bool act = (it * 64 + lane) < 2000;
        unsigned int n = (v[u].x > 0 ? 1u : 0u) | (v[u].y > 0 ? 2u : 0u)
                       | (v[u].z > 0 ? 4u : 0u) | (v[u].w > 0 ? 8u : 0u);
        n = act ? (n << sh) : 0u;
        n |= __shfl_xor(n, 1, 64);
        n |= __shfl_xor(n, 2, 64);
        n |= __shfl_xor(n, 4, 64);                 // all 8 lanes of group hold word
        const int wglob = it * 8 + w;
        if ((lane & 7) == 0 && wglob < 250)
          pkrow[wglob * 16] = n;
      }
    }
  } else {
    // ---- wh role: node-group nb = blockIdx.x/2, 4 waves = 4 nodes ----
    const int t = threadIdx.x;
    const int o = t & 63;
    const int n = (blockIdx.x >> 1) * 4 + (t >> 6);
    const float* hrow = hv + n * INF_;
    const float* Ws0 = Wsv + o;
    const float* Ws1 = Wsv + INF_ * OUTF + o;
    float a0a = 0.f, a0b = 0.f, a1a = 0.f, a1b = 0.f;
#pragma unroll 8
    for (int f = 0; f < INF_; f += 2) {
      float h0 = hrow[f], h1 = hrow[f + 1];
      a0a += h0 * Ws0[f * OUTF];
      a0b += h1 * Ws0[(f + 1) * OUTF];
      a1a += h0 * Ws1[f * OUTF];
      a1b += h1 * Ws1[(f + 1) * OUTF];
    }
    float acc0 = a0a + a0b, acc1 = a1a + a1b;
    Whf[(0 * NTOT + n) * OUTF + o] = acc0;
    Whf[(1 * NTOT + n) * OUTF + o] = acc1;
    float s10 = wave_sum(acc0 * ap[o]);
    float s20 = wave_sum(acc0 * ap[OUTF + o]);
    float s11 = wave_sum(acc1 * ap[2 * OUTF + o]);
    float s21 = wave_sum(acc1 * ap[3 * OUTF + o]);
    if (o == 0) {
      const float w20 = s20 * LOG2E, w21 = s21 * LOG2E;
      Wh1s[n] = s10 * LOG2E;        Wh2s[n] = w20;
      Wh1s[NTOT + n] = s11 * LOG2E; Wh2s[NTOT + n] = w21;
      E2pk[n]        = pk2(EXP2F(w20), EXP2F(ALPHA * w20)); // lo=E2p hi=E2n
      E2pk[NTOT + n] = pk2(EXP2F(w21), EXP2F(ALPHA * w21));
    }
  }
}

// ---------------- k_mid: blocks 0-1 = m2 (global max), 2..501 = bpack -------
__global__ __launch_bounds__(256)
void k_mid(const float* __restrict__ Whf, const float* __restrict__ Wh2s,
           float* __restrict__ M2s, int4* __restrict__ WhB) {
  if (blockIdx.x < 2) {
    const int hd = blockIdx.x;
    float mx = -1e30f;
    for (int i = threadIdx.x; i < NTOT; i += 256)
      mx = fmaxf(mx, Wh2s[hd * NTOT + i]);
    for (int d = 32; d; d >>= 1) mx = fmaxf(mx, __shfl_xor(mx, d, 64));
    __shared__ float red[4];
    if ((threadIdx.x & 63) == 0) red[threadIdx.x >> 6] = mx;
    __syncthreads();
    if (threadIdx.x == 0)
      M2s[hd] = fmaxf(fmaxf(red[0], red[1]), fmaxf(red[2], red[3]));
  } else {
    const int gid = (blockIdx.x - 2) * 256 + threadIdx.x;  // 128000 total
    const int lane = gid & 63;
    const int c = (gid >> 6) & 3;
    const int t = (gid >> 8) % 250;
    const int hd = gid / 64000;
    const int jb = t * 32 + (lane >> 4) * 8;
    const int col = c * 16 + (lane & 15);
    const float* src = Whf + (hd * NTOT + jb) * OUTF + col;
    B16x8 out;
#pragma unroll
    for (int e2 = 0; e2 < 4; ++e2)
      out.u[e2] = pack2_bf16(src[(2 * e2) * OUTF], src[(2 * e2 + 1) * OUTF]);
    WhB[gid] = out.i4;
  }
}

// ---------------- k_attn_mfma: grid=(250, njy), block=128 -------------------
// widx = HEAD (R25). Exp-free loop (R29). TWO rowblks per wave (R33):
// rowblks 2b and 2b+1 share each WhB/E2 tile -> L2 traffic halves.
__global__ __launch_bounds__(128)
void k_attn_mfma(const unsigned int* __restrict__ packed,
                 const float* __restrict__ Wh1s,
                 const float* __restrict__ M2s, const int4* __restrict__ WhB,
                 const unsigned int* __restrict__ E2pk,  // [2][8000]
                 float* __restrict__ partAcc,   // [njy][2][8000][64]
                 float* __restrict__ partS)     // [njy][2][8000]
{
  const int hd = threadIdx.x >> 6;               // head index (0/1)
  const int lane = threadIdx.x & 63;
  const int m = lane & 15;
  const int g = lane >> 4;
  const int kb = g * 8;
  const int rbA = blockIdx.x * 2;                // rowblks 0..499, pair
  const int rbB = rbA + 1;
  const int iA = rbA * 16 + m;
  const int iB = rbB * 16 + m;
  const int jy = blockIdx.y, njy = gridDim.y;
  const int t0 = (250 * jy) / njy, t1 = (250 * (jy + 1)) / njy;

  const unsigned int* pkbA = packed + rbA * 4000 + m;
  const unsigned int* pkbB = packed + rbB * 4000 + m;

  const float w1sA = Wh1s[hd * NTOT + iA];
  const float w1sB = Wh1s[hd * NTOT + iB];
  const float yA = w1sA + M2s[hd], yB = w1sB + M2s[hd];
  const float ciA = fmaxf(yA, ALPHA * yA), ciB = fmaxf(yB, ALPHA * yB);
  const float E1pA = EXP2F(w1sA - ciA), E1nA = EXP2F(fmaf(ALPHA, w1sA, -ciA));
  const float E1pB = EXP2F(w1sB - ciB), E1nB = EXP2F(fmaf(ALPHA, w1sB, -ciB));
  const unsigned int* e2 = E2pk + hd * NTOT;
  const int4* WhBh = WhB + hd * 64000;           // 250*256 frags per head

  f32x4 aA_0 = {0.f,0.f,0.f,0.f}, aA_1 = aA_0, aA_2 = aA_0, aA_3 = aA_0;
  f32x4 aB_0 = aA_0, aB_1 = aA_0, aB_2 = aA_0, aB_3 = aA_0;
  f32x4 svA = aA_0, svB = aA_0;                  // ones-MFMA row sums

  B16x8 ones;                                     // bf16 1.0 x8
#pragma unroll
  for (int e2i = 0; e2i < 4; ++e2i) ones.u[e2i] = 0x3F803F80u;

  struct Frags { int4 f[4]; uint4 ua, ub; };
  auto load_frags = [&](int t, Frags& F) {
    const int4* bp = WhBh + t * 256 + lane;
#pragma unroll
    for (int c = 0; c < 4; ++c) F.f[c] = bp[c * 64];
    const unsigned int* w0 = e2 + t * 32 + kb;
    F.ua = *(const uint4*)w0; F.ub = *(const uint4*)(w0 + 4);
  };

  auto compute = [&](unsigned int mwA, unsigned int mwB, const Frags& F) {
    const unsigned bitsA = (mwA >> kb) & 0xffu;
    const unsigned bitsB = (mwB >> kb) & 0xffu;
    const unsigned uv[8] = {F.ua.x, F.ua.y, F.ua.z, F.ua.w, F.ub.x, F.ub.y, F.ub.z, F.ub.w};
    float qA[8], qB[8];
#pragma unroll
    for (int e = 0; e < 8; ++e) {
      float p = __uint_as_float(uv[e] << 16);            // E2p (bf16->f32)
      float nn = __uint_as_float(uv[e] & 0xFFFF0000u);   // E2n
      float vA = fmaxf(E1pA * p, E1nA * nn);
      float vB = fmaxf(E1pB * p, E1nB * nn);
      qA[e] = ((bitsA >> e) & 1u) ? vA : 0.f;
      qB[e] = ((bitsB >> e) & 1u) ? vB : 0.f;
    }
    B16x8 afA, afB;
#pragma unroll
    for (int e2i = 0; e2i < 4; ++e2i) {
      afA.u[e2i] = pk2(qA[2 * e2i], qA[2 * e2i + 1]);
      afB.u[e2i] = pk2(qB[2 * e2i], qB[2 * e2i + 1]);
    }
    B16x8 b;
    b.i4 = F.f[0];
    aA_0 = __builtin_amdgcn_mfma_f32_16x16x32_bf16(afA.s8, b.s8, aA_0, 0, 0, 0);
    aB_0 = __builtin_amdgcn_mfma_f32_16x16x32_bf16(afB.s8, b.s8, aB_0, 0, 0, 0);
    b.i4 = F.f[1];
    aA_1 = __builtin_amdgcn_mfma_f32_16x16x32_bf16(afA.s8, b.s8, aA_1, 0, 0, 0);
    aB_1 = __builtin_amdgcn_mfma_f32_16x16x32_bf16(afB.s8, b.s8, aB_1, 0, 0, 0);
    b.i4 = F.f[2];
    aA_2 = __builtin_amdgcn_mfma_f32_16x16x32_bf16(afA.s8, b.s8, aA_2, 0, 0, 0);
    aB_2 = __builtin_amdgcn_mfma_f32_16x16x32_bf16(afB.s8, b.s8, aB_2, 0, 0, 0);
    b.i4 = F.f[3];
    aA_3 = __builtin_amdgcn_mfma_f32_16x16x32_bf16(afA.s8, b.s8, aA_3, 0, 0, 0);
    aB_3 = __builtin_amdgcn_mfma_f32_16x16x32_bf16(afB.s8, b.s8, aB_3, 0, 0, 0);
    svA = __builtin_amdgcn_mfma_f32_16x16x32_bf16(afA.s8, ones.s8, svA, 0, 0, 0);
    svB = __builtin_amdgcn_mfma_f32_16x16x32_bf16(afB.s8, ones.s8, svB, 0, 0, 0);
  };

  // pipeline: mask words 2 ahead; frags 1 ahead via named FA/FB (no copies)
  unsigned int mwA0 = pkbA[t0 * 16],                 mwB0 = pkbB[t0 * 16];
  unsigned int mwA1 = pkbA[min(t0 + 1, t1 - 1) * 16], mwB1 = pkbB[min(t0 + 1, t1 - 1) * 16];
  Frags FA, FB;
  load_frags(t0, FA);
  int t = t0;
  for (; t + 1 < t1; t += 2) {
    load_frags(t + 1, FB);
    const int tna = min(t + 2, t1 - 1);
    unsigned int mwAa = pkbA[tna * 16], mwBa = pkbB[tna * 16];
    compute(mwA0, mwB0, FA);
    mwA0 = mwA1; mwB0 = mwB1; mwA1 = mwAa; mwB1 = mwBa;
    load_frags(tna, FA);
    const int tnb = min(t + 3, t1 - 1);
    unsigned int mwAb = pkbA[tnb * 16], mwBb = pkbB[tnb * 16];
    compute(mwA0, mwB0, FB);
    mwA0 = mwA1; mwB0 = mwB1; mwA1 = mwAb; mwB1 = mwBb;
  }
  if (t < t1) compute(mwA0, mwB0, FA);           // odd-length tail (FA = t1-1)

  // direct stores of both rowblk partials -- no LDS, no barrier
  const int baseA = (jy * 2 + hd) * NTOT + rbA * 16;
  const int baseB = (jy * 2 + hd) * NTOT + rbB * 16;
  if (m == 0) {
#pragma unroll
    for (int q = 0; q < 4; ++q) {
      partS[baseA + g * 4 + q] = svA[q];
      partS[baseB + g * 4 + q] = svB[q];
    }
  }
  // C layout: col = lane&15 (feature), row = g*4 + q (node)
  float* oA = partAcc + baseA * OUTF;
  float* oB = partAcc + baseB * OUTF;
#pragma unroll
  for (int q = 0; q < 4; ++q) {
    const int row = g * 4 + q;
    oA[row * OUTF +      m] = aA_0[q];
    oA[row * OUTF + 16 + m] = aA_1[q];
    oA[row * OUTF + 32 + m] = aA_2[q];
    oA[row * OUTF + 48 + m] = aA_3[q];
    oB[row * OUTF +      m] = aB_0[q];
    oB[row * OUTF + 16 + m] = aB_1[q];
    oB[row * OUTF + 32 + m] = aB_2[q];
    oB[row * OUTF + 48 + m] = aB_3[q];
  }
}

// ---------------- k_final: combine njy + /s + ELU + log_softmax + store -----
__global__ void k_final(const float* __restrict__ partAcc, const float* __restrict__ partS,
                        int njy, float* __restrict__ out) {
  const int wave = threadIdx.x >> 6, lane = threadIdx.x & 63;
  const int n = blockIdx.x * 4 + wave;
  float x[2];
#pragma unroll
  for (int hd = 0; hd < 2; ++hd) {
    float a = 0.f, s = 0.f;
    for (int jy = 0; jy < njy; ++jy) {
      a += partAcc[((jy * 2 + hd) * NTOT + n) * OUTF + lane];
      s += partS[(jy * 2 + hd) * NTOT + n];
    }
    float mid = a / s;
    x[hd] = mid > 0.f ? mid : (__expf(mid) - 1.f);   // ELU(alpha=1)
  }
  float mx = fmaxf(x[0], x[1]);
  for (int d = 32; d; d >>= 1) mx = fmaxf(mx, __shfl_xor(mx, d, 64));
  float se = __expf(x[0] - mx) + __expf(x[1] - mx);
  for (int d = 32; d; d >>= 1) se += __shfl_xor(se, d, 64);
  const float lse = mx + __logf(se);
  const int orow = (n >= CN1 + CN2) ? (n - CN1 - CN2) : (n + CN3);
  out[orow * 128 + lane]      = x[0] - lse;
  out[orow * 128 + 64 + lane] = x[1] - lse;
}

__global__ void k_sentinel(float* __restrict__ out, float v) {
  out[blockIdx.x * 256 + threadIdx.x] = v;
}

// ---------------------------------------------------------------------------
extern "C" void kernel_launch(void* const* d_in, const int* in_sizes, int n_in,
                              void* d_out, int out_size, void* d_ws, size_t ws_size,
                              hipStream_t stream) {
  float* outf = (float*)d_out;

  static const int EXP[12] = {1024000, 9000000, 6250000, 6250000, 7500000, 7500000,
                              6250000, 7500000, 7500000, 6250000, 16384, 256};
  bool exact = (n_in == 12);
  if (exact) for (int i = 0; i < 12; ++i) if (in_sizes[i] != EXP[i]) { exact = false; break; }

  // ws layout: Wh1s 64000 | Wh2s 64000 | M2s 256 | E2pk 64000 | WhB 2,048,000 |
  //            packed 8,000,000 | partS njy*64,000 |
  //            Whf 4,096,000 / partAcc njy*4,096,000 (overlay)
  const size_t FIXED = 64000 + 64000 + 256 + 64000 + 2048000 + 8000000; // 10,240,256
  int njy = 0;
  for (int cand = 8; cand >= 1; cand >>= 1) {
    size_t need = FIXED + (size_t)cand * 64000 + (size_t)cand * 4096000;
    if (ws_size >= need) { njy = cand; break; }
  }
  if (!exact || njy == 0) {
    k_sentinel<<<dim3(4000), dim3(256), 0, stream>>>(outf, -148.0f);
    return;
  }

  const float* h  = (const float*)d_in[0];
  const int* A1  = (const int*)d_in[1];
  const int* A2  = (const int*)d_in[2];
  const int* A3  = (const int*)d_in[3];
  const int* A12 = (const int*)d_in[4];
  const int* A13 = (const int*)d_in[5];
  const int* A23 = (const int*)d_in[6];
  const int* A21 = (const int*)d_in[7];
  const int* A31 = (const int*)d_in[8];
  const int* A32 = (const int*)d_in[9];
  const float* Ws = (const float*)d_in[10];
  const float* ap = (const float*)d_in[11];

  char* w = (char*)d_ws;
  float*        Wh1s    = (float*)(w);
  float*        Wh2s    = (float*)(w + 64000);
  float*        M2s     = (float*)(w + 128000);
  unsigned int* E2pk    = (unsigned int*)(w + 128256);
  int4*         WhB     = (int4*) (w + 192256);
  unsigned int* packed  = (unsigned int*)(w + 2240256);
  float*        partS   = (float*)(w + 10240256);
  float*        Whf     = (float*)(w + 10240256 + (size_t)njy * 64000);
  float*        partAcc = Whf;                    // overlay (Whf dead after k_mid)

  k_front    <<<dim3(4000),     dim3(256), 0, stream>>>(A1, A12, A13, A21, A2, A23, A31, A32, A3,
                                                        packed, h, Ws, ap, Whf, Wh1s, Wh2s, E2pk);
  k_mid      <<<dim3(502),      dim3(256), 0, stream>>>(Whf, Wh2s, M2s, WhB);
  k_attn_mfma<<<dim3(250, njy), dim3(128), 0, stream>>>(packed, Wh1s, M2s, WhB, E2pk,
                                                        partAcc, partS);
  k_final    <<<dim3(2000),     dim3(256), 0, stream>>>(partAcc, partS, njy, outf);
}

// Round 15
// 329.043 us; speedup vs baseline: 1.0151x; 1.0014x over previous
//
#include <hip/hip_runtime.h>
#include <hip/hip_bf16.h>

// ---------------------------------------------------------------------------
// ROUND 34: delete k_mid's bpack -- k_front's wh role emits WhB fragments
// DIRECTLY. Key insight: a wave computing 8 consecutive nodes x (col=lane)
// holds exactly one WhB int4 per lane (nodes tg*32+wv*8..+7, col lane) --
// no cross-lane transpose. wh role = 500 units (head, tgroup); 4 waves x
// 8 nodes; lane packs acc[8] -> int4 at [hd*64000+tg*256+(lane>>4)*64+
// wv*16+(lane&15)]; Wh1s/Wh2s/E2pk via 16 wave_sums. Eliminates Whf
// entirely (4MB wr + 4MB rd) and bpack's 500 blocks; k_mid shrinks to
// 2-block k_m2. Grid 2500 = 4 pack : 1 wh. Same FLOPs, hidden under the
// 78us pack stream. k_attn/k_final = R33 verbatim.
// Predict: k_front ~78 unchanged, k_mid(~10)->k_m2(~3), total 329.5 ->
// ~320-324. If <4us gain, middle is smaller than estimated -> plateau.
// Carried: pack||wh fusion + 16-deep NT batch (R31), one-head waves (R25),
// packed-E2 exp-free loop (R29), 2-rowblk k_attn (R33).
// ---------------------------------------------------------------------------

#define CN1 3000
#define CN2 2500
#define CN3 2500
#define NTOT 8000
#define INF_ 128
#define OUTF 64
#define LOG2E 1.44269504088896340736f
#define ALPHA 0.2f

typedef __attribute__((ext_vector_type(4))) float f32x4;
typedef __attribute__((ext_vector_type(8))) short short8;
typedef __attribute__((ext_vector_type(4))) int i32x4;
union B16x8 { int4 i4; short8 s8; unsigned int u[4]; };

#if defined(__has_builtin)
#if __has_builtin(__builtin_amdgcn_exp2f)
#define EXP2F(x) __builtin_amdgcn_exp2f(x)
#endif
#endif
#ifndef EXP2F
#define EXP2F(x) exp2f(x)
#endif

__device__ inline float wave_sum(float v) {
  for (int d = 32; d; d >>= 1) v += __shfl_xor(v, d, 64);
  return v;
}

// packed RNE f32x2 -> bf16x2 (v_cvt_pk_bf16_f32 on gfx950 via hip header)
__device__ inline unsigned int pk2(float a, float b) {
  union { __hip_bfloat162 h; unsigned int u; } cv;
  cv.h = __float22bfloat162_rn(make_float2(a, b));
  return cv.u;
}

// ---------------- k_front: blockIdx%5<4 = mask-pack, %5==4 = Wh+frags -------
__global__ __launch_bounds__(256)
void k_front(const int* __restrict__ A1,  const int* __restrict__ A12, const int* __restrict__ A13,
             const int* __restrict__ A21, const int* __restrict__ A2,  const int* __restrict__ A23,
             const int* __restrict__ A31, const int* __restrict__ A32, const int* __restrict__ A3,
             unsigned int* __restrict__ packed,
             const float* __restrict__ hv, const float* __restrict__ Wsv,
             const float* __restrict__ ap,
             float* __restrict__ Wh1s,   // [2][8000] = (Wh·a1)*log2e
             float* __restrict__ Wh2s,   // [2][8000] = (Wh·a2)*log2e (for m2)
             unsigned int* __restrict__ E2pk,   // [2][8000] packed bf16 pair
             int4* __restrict__ WhB) {   // [2][250][256] MFMA B-frags
  const int role = blockIdx.x % 5;
  if (role < 4) {
    // ---- pack role: pk = (blockIdx/5)*4 + role, 4 waves = 4 rows ----
    const int i = ((blockIdx.x / 5) * 4 + role) * 4 + (threadIdx.x >> 6);
    const int lane = threadIdx.x & 63;
    const int *r0, *r1, *r2;
    if (i < CN1)            { r0 = A1  + i * CN1;          r1 = A12 + i * CN2;          r2 = A13 + i * CN3; }
    else if (i < CN1 + CN2) { int r = i - CN1;       r0 = A21 + r * CN1; r1 = A2  + r * CN2; r2 = A23 + r * CN3; }
    else                    { int r = i - CN1 - CN2; r0 = A31 + r * CN1; r1 = A32 + r * CN2; r2 = A3  + r * CN3; }
    const i32x4* p0 = (const i32x4*)r0;   // 750 int4 (cols    0..2999)
    const i32x4* p1 = (const i32x4*)r1;   // 625 int4 (cols 3000..5499)
    const i32x4* p2 = (const i32x4*)r2;   // 625 int4 (cols 5500..7999)
    unsigned int* pkrow = packed + (i >> 4) * 4000 + (i & 15);
    const int sh = 4 * (lane & 7);
    const int w  = lane >> 3;
#pragma unroll
    for (int ob = 0; ob < 2; ++ob) {
      i32x4 v[16];
#pragma unroll
      for (int u = 0; u < 16; ++u) {
        int q = (ob * 16 + u) * 64 + lane;
        q = q < 2000 ? q : 1999;                   // clamp (it=31 partial)
        const i32x4* src = (q < 750) ? (p0 + q) : (q < 1375) ? (p1 + q - 750) : (p2 + q - 1375);
        v[u] = __builtin_nontemporal_load(src);
      }
#pragma unroll
      for (int u = 0; u < 16; ++u) {
        const int it = ob * 16 + u;
        const bool act = (it * 64 + lane) < 2000;
        unsigned int n = (v[u].x > 0 ? 1u : 0u) | (v[u].y > 0 ? 2u : 0u)
                       | (v[u].z > 0 ? 4u : 0u) | (v[u].w > 0 ? 8u : 0u);
        n = act ? (n << sh) : 0u;
        n |= __shfl_xor(n, 1, 64);
        n |= __shfl_xor(n, 2, 64);
        n |= __shfl_xor(n, 4, 64);                 // all 8 lanes of group hold word
        const int wglob = it * 8 + w;
        if ((lane & 7) == 0 && wglob < 250)
          pkrow[wglob * 16] = n;
      }
    }
  } else {
    // ---- wh role: unit u = blockIdx/5 (0..499): head hd=u&1, tgroup tg=u>>1
    const int u = blockIdx.x / 5;
    const int hd = u & 1;
    const int tg = u >> 1;                         // 0..249
    const int wv = threadIdx.x >> 6;               // wave = node-group of 8
    const int lane = threadIdx.x & 63;             // lane = output column
    const int n0 = tg * 32 + wv * 8;
    const float* Wsh = Wsv + hd * (INF_ * OUTF) + lane;
    const float* h0 = hv + n0 * INF_;
    float acc[8] = {0.f,0.f,0.f,0.f,0.f,0.f,0.f,0.f};
#pragma unroll 4
    for (int f = 0; f < INF_; ++f) {
      const float wsv = Wsh[f * OUTF];
#pragma unroll
      for (int k = 0; k < 8; ++k)
        acc[k] = fmaf(h0[k * INF_ + f], wsv, acc[k]);
    }
    // direct B-frag store: nodes n0..n0+7 at col=lane as 4 bf16 pairs
    B16x8 fr;
#pragma unroll
    for (int e = 0; e < 4; ++e) fr.u[e] = pk2(acc[2 * e], acc[2 * e + 1]);
    WhB[hd * 64000 + tg * 256 + (lane >> 4) * 64 + wv * 16 + (lane & 15)] = fr.i4;
    // per-node scalar sums (a1, a2) -> Wh1s/Wh2s/E2pk
    const float a1v = ap[hd * 128 + lane];
    const float a2v = ap[hd * 128 + 64 + lane];
#pragma unroll
    for (int k = 0; k < 8; ++k) {
      float s1 = wave_sum(acc[k] * a1v);
      float s2 = wave_sum(acc[k] * a2v);
      if (lane == 0) {
        const int n = n0 + k;
        const float w2 = s2 * LOG2E;
        Wh1s[hd * NTOT + n] = s1 * LOG2E;
        Wh2s[hd * NTOT + n] = w2;
        E2pk[hd * NTOT + n] = pk2(EXP2F(w2), EXP2F(ALPHA * w2));
      }
    }
  }
}

// ---------------- k_m2: 2 blocks, per-head global max of Wh2s ---------------
__global__ __launch_bounds__(256)
void k_m2(const float* __restrict__ Wh2s, float* __restrict__ M2s) {
  const int hd = blockIdx.x;
  float mx = -1e30f;
  for (int i = threadIdx.x; i < NTOT; i += 256)
    mx = fmaxf(mx, Wh2s[hd * NTOT + i]);
  for (int d = 32; d; d >>= 1) mx = fmaxf(mx, __shfl_xor(mx, d, 64));
  __shared__ float red[4];
  if ((threadIdx.x & 63) == 0) red[threadIdx.x >> 6] = mx;
  __syncthreads();
  if (threadIdx.x == 0)
    M2s[hd] = fmaxf(fmaxf(red[0], red[1]), fmaxf(red[2], red[3]));
}

// ---------------- k_attn_mfma: grid=(250, njy), block=128 (R33) -------------
// widx = HEAD (R25). Exp-free loop (R29). TWO rowblks per wave (R33).
__global__ __launch_bounds__(128)
void k_attn_mfma(const unsigned int* __restrict__ packed,
                 const float* __restrict__ Wh1s,
                 const float* __restrict__ M2s, const int4* __restrict__ WhB,
                 const unsigned int* __restrict__ E2pk,  // [2][8000]
                 float* __restrict__ partAcc,   // [njy][2][8000][64]
                 float* __restrict__ partS)     // [njy][2][8000]
{
  const int hd = threadIdx.x >> 6;               // head index (0/1)
  const int lane = threadIdx.x & 63;
  const int m = lane & 15;
  const int g = lane >> 4;
  const int kb = g * 8;
  const int rbA = blockIdx.x * 2;                // rowblks 0..499, pair
  const int rbB = rbA + 1;
  const int iA = rbA * 16 + m;
  const int iB = rbB * 16 + m;
  const int jy = blockIdx.y, njy = gridDim.y;
  const int t0 = (250 * jy) / njy, t1 = (250 * (jy + 1)) / njy;

  const unsigned int* pkbA = packed + rbA * 4000 + m;
  const unsigned int* pkbB = packed + rbB * 4000 + m;

  const float w1sA = Wh1s[hd * NTOT + iA];
  const float w1sB = Wh1s[hd * NTOT + iB];
  const float yA = w1sA + M2s[hd], yB = w1sB + M2s[hd];
  const float ciA = fmaxf(yA, ALPHA * yA), ciB = fmaxf(yB, ALPHA * yB);
  const float E1pA = EXP2F(w1sA - ciA), E1nA = EXP2F(fmaf(ALPHA, w1sA, -ciA));
  const float E1pB = EXP2F(w1sB - ciB), E1nB = EXP2F(fmaf(ALPHA, w1sB, -ciB));
  const unsigned int* e2 = E2pk + hd * NTOT;
  const int4* WhBh = WhB + hd * 64000;           // 250*256 frags per head

  f32x4 aA_0 = {0.f,0.f,0.f,0.f}, aA_1 = aA_0, aA_2 = aA_0, aA_3 = aA_0;
  f32x4 aB_0 = aA_0, aB_1 = aA_0, aB_2 = aA_0, aB_3 = aA_0;
  f32x4 svA = aA_0, svB = aA_0;                  // ones-MFMA row sums

  B16x8 ones;                                     // bf16 1.0 x8
#pragma unroll
  for (int e2i = 0; e2i < 4; ++e2i) ones.u[e2i] = 0x3F803F80u;

  struct Frags { int4 f[4]; uint4 ua, ub; };
  auto load_frags = [&](int t, Frags& F) {
    const int4* bp = WhBh + t * 256 + lane;
#pragma unroll
    for (int c = 0; c < 4; ++c) F.f[c] = bp[c * 64];
    const unsigned int* w0 = e2 + t * 32 + kb;
    F.ua = *(const uint4*)w0; F.ub = *(const uint4*)(w0 + 4);
  };

  auto compute = [&](unsigned int mwA, unsigned int mwB, const Frags& F) {
    const unsigned bitsA = (mwA >> kb) & 0xffu;
    const unsigned bitsB = (mwB >> kb) & 0xffu;
    const unsigned uv[8] = {F.ua.x, F.ua.y, F.ua.z, F.ua.w, F.ub.x, F.ub.y, F.ub.z, F.ub.w};
    float qA[8], qB[8];
#pragma unroll
    for (int e = 0; e < 8; ++e) {
      float p = __uint_as_float(uv[e] << 16);            // E2p (bf16->f32)
      float nn = __uint_as_float(uv[e] & 0xFFFF0000u);   // E2n
      float vA = fmaxf(E1pA * p, E1nA * nn);
      float vB = fmaxf(E1pB * p, E1nB * nn);
      qA[e] = ((bitsA >> e) & 1u) ? vA : 0.f;
      qB[e] = ((bitsB >> e) & 1u) ? vB : 0.f;
    }
    B16x8 afA, afB;
#pragma unroll
    for (int e2i = 0; e2i < 4; ++e2i) {
      afA.u[e2i] = pk2(qA[2 * e2i], qA[2 * e2i + 1]);
      afB.u[e2i] = pk2(qB[2 * e2i], qB[2 * e2i + 1]);
    }
    B16x8 b;
    b.i4 = F.f[0];
    aA_0 = __builtin_amdgcn_mfma_f32_16x16x32_bf16(afA.s8, b.s8, aA_0, 0, 0, 0);
    aB_0 = __builtin_amdgcn_mfma_f32_16x16x32_bf16(afB.s8, b.s8, aB_0, 0, 0, 0);
    b.i4 = F.f[1];
    aA_1 = __builtin_amdgcn_mfma_f32_16x16x32_bf16(afA.s8, b.s8, aA_1, 0, 0, 0);
    aB_1 = __builtin_amdgcn_mfma_f32_16x16x32_bf16(afB.s8, b.s8, aB_1, 0, 0, 0);
    b.i4 = F.f[2];
    aA_2 = __builtin_amdgcn_mfma_f32_16x16x32_bf16(afA.s8, b.s8, aA_2, 0, 0, 0);
    aB_2 = __builtin_amdgcn_mfma_f32_16x16x32_bf16(afB.s8, b.s8, aB_2, 0, 0, 0);
    b.i4 = F.f[3];
    aA_3 = __builtin_amdgcn_mfma_f32_16x16x32_bf16(afA.s8, b.s8, aA_3, 0, 0, 0);
    aB_3 = __builtin_amdgcn_mfma_f32_16x16x32_bf16(afB.s8, b.s8, aB_3, 0, 0, 0);
    svA = __builtin_amdgcn_mfma_f32_16x16x32_bf16(afA.s8, ones.s8, svA, 0, 0, 0);
    svB = __builtin_amdgcn_mfma_f32_16x16x32_bf16(afB.s8, ones.s8, svB, 0, 0, 0);
  };

  // pipeline: mask words 2 ahead; frags 1 ahead via named FA/FB (no copies)
  unsigned int mwA0 = pkbA[t0 * 16],                 mwB0 = pkbB[t0 * 16];
  unsigned int mwA1 = pkbA[min(t0 + 1, t1 - 1) * 16], mwB1 = pkbB[min(t0 + 1, t1 - 1) * 16];
  Frags FA, FB;
  load_frags(t0, FA);
  int t = t0;
  for (; t + 1 < t1; t += 2) {
    load_frags(t + 1, FB);
    const int tna = min(t + 2, t1 - 1);
    unsigned int mwAa = pkbA[tna * 16], mwBa = pkbB[tna * 16];
    compute(mwA0, mwB0, FA);
    mwA0 = mwA1; mwB0 = mwB1; mwA1 = mwAa; mwB1 = mwBa;
    load_frags(tna, FA);
    const int tnb = min(t + 3, t1 - 1);
    unsigned int mwAb = pkbA[tnb * 16], mwBb = pkbB[tnb * 16];
    compute(mwA0, mwB0, FB);
    mwA0 = mwA1; mwB0 = mwB1; mwA1 = mwAb; mwB1 = mwBb;
  }
  if (t < t1) compute(mwA0, mwB0, FA);           // odd-length tail (FA = t1-1)

  // direct stores of both rowblk partials -- no LDS, no barrier
  const int baseA = (jy * 2 + hd) * NTOT + rbA * 16;
  const int baseB = (jy * 2 + hd) * NTOT + rbB * 16;
  if (m == 0) {
#pragma unroll
    for (int q = 0; q < 4; ++q) {
      partS[baseA + g * 4 + q] = svA[q];
      partS[baseB + g * 4 + q] = svB[q];
    }
  }
  // C layout: col = lane&15 (feature), row = g*4 + q (node)
  float* oA = partAcc + baseA * OUTF;
  float* oB = partAcc + baseB * OUTF;
#pragma unroll
  for (int q = 0; q < 4; ++q) {
    const int row = g * 4 + q;
    oA[row * OUTF +      m] = aA_0[q];
    oA[row * OUTF + 16 + m] = aA_1[q];
    oA[row * OUTF + 32 + m] = aA_2[q];
    oA[row * OUTF + 48 + m] = aA_3[q];
    oB[row * OUTF +      m] = aB_0[q];
    oB[row * OUTF + 16 + m] = aB_1[q];
    oB[row * OUTF + 32 + m] = aB_2[q];
    oB[row * OUTF + 48 + m] = aB_3[q];
  }
}

// ---------------- k_final: combine njy + /s + ELU + log_softmax + store -----
__global__ void k_final(const float* __restrict__ partAcc, const float* __restrict__ partS,
                        int njy, float* __restrict__ out) {
  const int wave = threadIdx.x >> 6, lane = threadIdx.x & 63;
  const int n = blockIdx.x * 4 + wave;
  float x[2];
#pragma unroll
  for (int hd = 0; hd < 2; ++hd) {
    float a = 0.f, s = 0.f;
    for (int jy = 0; jy < njy; ++jy) {
      a += partAcc[((jy * 2 + hd) * NTOT + n) * OUTF + lane];
      s += partS[(jy * 2 + hd) * NTOT + n];
    }
    float mid = a / s;
    x[hd] = mid > 0.f ? mid : (__expf(mid) - 1.f);   // ELU(alpha=1)
  }
  float mx = fmaxf(x[0], x[1]);
  for (int d = 32; d; d >>= 1) mx = fmaxf(mx, __shfl_xor(mx, d, 64));
  float se = __expf(x[0] - mx) + __expf(x[1] - mx);
  for (int d = 32; d; d >>= 1) se += __shfl_xor(se, d, 64);
  const float lse = mx + __logf(se);
  const int orow = (n >= CN1 + CN2) ? (n - CN1 - CN2) : (n + CN3);
  out[orow * 128 + lane]      = x[0] - lse;
  out[orow * 128 + 64 + lane] = x[1] - lse;
}

__global__ void k_sentinel(float* __restrict__ out, float v) {
  out[blockIdx.x * 256 + threadIdx.x] = v;
}

// ---------------------------------------------------------------------------
extern "C" void kernel_launch(void* const* d_in, const int* in_sizes, int n_in,
                              void* d_out, int out_size, void* d_ws, size_t ws_size,
                              hipStream_t stream) {
  float* outf = (float*)d_out;

  static const int EXP[12] = {1024000, 9000000, 6250000, 6250000, 7500000, 7500000,
                              6250000, 7500000, 7500000, 6250000, 16384, 256};
  bool exact = (n_in == 12);
  if (exact) for (int i = 0; i < 12; ++i) if (in_sizes[i] != EXP[i]) { exact = false; break; }

  // ws layout: Wh1s 64000 | Wh2s 64000 | M2s 256 | E2pk 64000 | WhB 2,048,000 |
  //            packed 8,000,000 | partS njy*64,000 | partAcc njy*4,096,000
  const size_t FIXED = 64000 + 64000 + 256 + 64000 + 2048000 + 8000000; // 10,240,256
  int njy = 0;
  for (int cand = 8; cand >= 1; cand >>= 1) {
    size_t need = FIXED + (size_t)cand * 64000 + (size_t)cand * 4096000;
    if (ws_size >= need) { njy = cand; break; }
  }
  if (!exact || njy == 0) {
    k_sentinel<<<dim3(4000), dim3(256), 0, stream>>>(outf, -148.0f);
    return;
  }

  const float* h  = (const float*)d_in[0];
  const int* A1  = (const int*)d_in[1];
  const int* A2  = (const int*)d_in[2];
  const int* A3  = (const int*)d_in[3];
  const int* A12 = (const int*)d_in[4];
  const int* A13 = (const int*)d_in[5];
  const int* A23 = (const int*)d_in[6];
  const int* A21 = (const int*)d_in[7];
  const int* A31 = (const int*)d_in[8];
  const int* A32 = (const int*)d_in[9];
  const float* Ws = (const float*)d_in[10];
  const float* ap = (const float*)d_in[11];

  char* w = (char*)d_ws;
  float*        Wh1s    = (float*)(w);
  float*        Wh2s    = (float*)(w + 64000);
  float*        M2s     = (float*)(w + 128000);
  unsigned int* E2pk    = (unsigned int*)(w + 128256);
  int4*         WhB     = (int4*) (w + 192256);
  unsigned int* packed  = (unsigned int*)(w + 2240256);
  float*        partS   = (float*)(w + 10240256);
  float*        partAcc = (float*)(w + 10240256 + (size_t)njy * 64000);

  k_front    <<<dim3(2500),     dim3(256), 0, stream>>>(A1, A12, A13, A21, A2, A23, A31, A32, A3,
                                                        packed, h, Ws, ap, Wh1s, Wh2s, E2pk, WhB);
  k_m2       <<<dim3(2),        dim3(256), 0, stream>>>(Wh2s, M2s);
  k_attn_mfma<<<dim3(250, njy), dim3(128), 0, stream>>>(packed, Wh1s, M2s, WhB, E2pk,
                                                        partAcc, partS);
  k_final    <<<dim3(2000),     dim3(256), 0, stream>>>(partAcc, partS, njy, outf);
}